// Round 1
// baseline (608.702 us; speedup 1.0000x reference)
//
#include <hip/hip_runtime.h>

#define BATCH 8
#define SEQ   2048
#define DIM   1024   // D == H == 1024

typedef __attribute__((ext_vector_type(8))) short short8;
typedef __attribute__((ext_vector_type(4))) float floatx4;

__device__ __forceinline__ unsigned short f32_to_bf16(float f) {
    union { float f; unsigned int u; } x; x.f = f;
    unsigned int r = x.u + 0x7fffu + ((x.u >> 16) & 1u);
    return (unsigned short)(r >> 16);
}

__device__ __forceinline__ float bf16_to_f32(unsigned short h) {
    union { unsigned int u; float f; } x; x.u = ((unsigned int)h) << 16;
    return x.f;
}

// async 16B/lane global->LDS. lds ptr must be wave-uniform; HW scatters lane i at base+16*i.
__device__ __forceinline__ void async_load16(const void* g, void* l) {
    __builtin_amdgcn_global_load_lds(
        (const __attribute__((address_space(1))) void*)g,
        (__attribute__((address_space(3))) void*)l, 16, 0, 0);
}

// ---------------------------------------------------------------------------
// Generic C = A @ B^T (+bias) * scale.  A: MxK (f32 or bf16), Bt: NxK (bf16),
// C: MxN (bf16 or f32).  128x128 block tile, BK=32, 256 threads (4 waves 2x2),
// each wave does 4x4 tiles of v_mfma_f32_16x16x32_bf16.
// M,N multiples of 128; K multiple of 32.
// ---------------------------------------------------------------------------
template<bool A_F32, bool C_BF16, bool BIAS>
__global__ __launch_bounds__(256) void gemm_bt(
    const void* __restrict__ Ap, const unsigned short* __restrict__ Bt,
    void* __restrict__ Cp, const float* __restrict__ bias,
    int M, int N, int K, long sA, long sB, long sC, float scale)
{
    __shared__ unsigned short As[128 * 32];
    __shared__ unsigned short Bs[128 * 32];

    const int tid  = threadIdx.x;
    const int lane = tid & 63;
    const int wave = tid >> 6;
    const int wm   = wave >> 1;       // 0..1
    const int wn   = wave & 1;        // 0..1
    const int l15  = lane & 15;
    const int quad = lane >> 4;       // 0..3
    const int row0 = blockIdx.x * 128;
    const int col0 = blockIdx.y * 128;
    const long zA = (long)blockIdx.z * sA;
    const long zB = (long)blockIdx.z * sB;
    const long zC = (long)blockIdx.z * sC;

    // staging coords within a 16-row x 32-col chunk (one wave-call = 1KB)
    const int srow = lane >> 2;          // 0..15
    const int scol = (lane & 3) * 8;     // 0,8,16,24

    floatx4 acc[4][4];
    const floatx4 zed = {0.f, 0.f, 0.f, 0.f};
#pragma unroll
    for (int a = 0; a < 4; ++a)
#pragma unroll
        for (int b = 0; b < 4; ++b) acc[a][b] = zed;

    for (int kt = 0; kt < K; kt += 32) {
        // ---- stage A tile (128x32) ----
#pragma unroll
        for (int c = 0; c < 2; ++c) {
            const int chunk = wave * 2 + c;          // 0..7
            const int arow  = chunk * 16 + srow;     // 0..127
            if (A_F32) {
                const float* Af = (const float*)Ap + zA + (long)(row0 + arow) * K + kt + scol;
                floatx4 v0 = *(const floatx4*)Af;
                floatx4 v1 = *(const floatx4*)(Af + 4);
                short8 w;
#pragma unroll
                for (int j = 0; j < 4; ++j) w[j]     = (short)f32_to_bf16(v0[j]);
#pragma unroll
                for (int j = 0; j < 4; ++j) w[4 + j] = (short)f32_to_bf16(v1[j]);
                *(short8*)(As + chunk * 512 + lane * 8) = w;
            } else {
                const unsigned short* Ab = (const unsigned short*)Ap + zA + (long)(row0 + arow) * K + kt + scol;
                async_load16(Ab, As + chunk * 512);
            }
        }
        // ---- stage B tile (128x32) ----
#pragma unroll
        for (int c = 0; c < 2; ++c) {
            const int chunk = wave * 2 + c;
            const int brow  = chunk * 16 + srow;
            const unsigned short* Bp = Bt + zB + (long)(col0 + brow) * K + kt + scol;
            async_load16(Bp, Bs + chunk * 512);
        }
        __syncthreads();

        short8 af[4], bf[4];
#pragma unroll
        for (int t = 0; t < 4; ++t) {
            af[t] = *(const short8*)(As + (wm * 64 + t * 16 + l15) * 32 + quad * 8);
            bf[t] = *(const short8*)(Bs + (wn * 64 + t * 16 + l15) * 32 + quad * 8);
        }
#pragma unroll
        for (int tm = 0; tm < 4; ++tm)
#pragma unroll
            for (int tn = 0; tn < 4; ++tn)
                acc[tm][tn] = __builtin_amdgcn_mfma_f32_16x16x32_bf16(af[tm], bf[tn], acc[tm][tn], 0, 0, 0);
        __syncthreads();
    }

    // ---- epilogue: C/D layout row = quad*4+reg, col = lane&15 ----
#pragma unroll
    for (int tn = 0; tn < 4; ++tn) {
        const int ccol = col0 + wn * 64 + tn * 16 + l15;
        float bv = 0.f;
        if (BIAS) bv = bias[ccol];
#pragma unroll
        for (int tm = 0; tm < 4; ++tm) {
            const int crow = row0 + wm * 64 + tm * 16 + quad * 4;
#pragma unroll
            for (int r = 0; r < 4; ++r) {
                float v = acc[tm][tn][r] * scale + bv;
                long ci = zC + (long)(crow + r) * N + ccol;
                if (C_BF16) ((unsigned short*)Cp)[ci] = f32_to_bf16(v);
                else        ((float*)Cp)[ci] = v;
            }
        }
    }
}

// ---------------------------------------------------------------------------
// transpose + f32->bf16:  src R x C (row-major, f32) -> dst C x R (bf16)
// ---------------------------------------------------------------------------
__global__ __launch_bounds__(256) void transpose_cvt(
    const float* __restrict__ src, unsigned short* __restrict__ dst,
    int R, int C, long sstride, long dstride)
{
    __shared__ float tile[32][33];
    const long sbase = (long)blockIdx.z * sstride;
    const long dbase = (long)blockIdx.z * dstride;
    const int c0 = blockIdx.x * 32;
    const int r0 = blockIdx.y * 32;
    const int tx = threadIdx.x & 31, ty = threadIdx.x >> 5;   // ty 0..7
#pragma unroll
    for (int i = 0; i < 32; i += 8)
        tile[ty + i][tx] = src[sbase + (long)(r0 + ty + i) * C + c0 + tx];
    __syncthreads();
#pragma unroll
    for (int i = 0; i < 32; i += 8)
        dst[dbase + (long)(c0 + ty + i) * R + r0 + tx] = f32_to_bf16(tile[tx][ty + i]);
}

// ---------------------------------------------------------------------------
// per-batch sum of input_k rows where mask <= 0.5 (atomic partial sums)
// grid (B, D/256, L/256), block 256
// ---------------------------------------------------------------------------
__global__ __launch_bounds__(256) void masked_sum(
    const float* __restrict__ xk, const float* __restrict__ mask, float* __restrict__ mavg)
{
    const int b = blockIdx.x;
    const int d = blockIdx.y * 256 + threadIdx.x;
    const int j0 = blockIdx.z * 256;
    const float* xb = xk + (long)b * SEQ * DIM;
    const float* mb = mask + b * SEQ;
    float s = 0.f;
    for (int j = j0; j < j0 + 256; ++j) {
        float mv = mb[j];
        float v  = xb[(long)j * DIM + d];
        s += (mv <= 0.5f) ? v : 0.f;
    }
    atomicAdd(&mavg[b * DIM + d], s);
}

__global__ __launch_bounds__(256) void count_masked(const float* __restrict__ mask, int* __restrict__ counts)
{
    const int b = blockIdx.x;
    int c = 0;
    for (int j = threadIdx.x; j < SEQ; j += 256) c += (mask[b * SEQ + j] <= 0.5f) ? 1 : 0;
    for (int o = 32; o; o >>= 1) c += __shfl_xor(c, o);
    __shared__ int r[4];
    if ((threadIdx.x & 63) == 0) r[threadIdx.x >> 6] = c;
    __syncthreads();
    if (threadIdx.x == 0) counts[b] = r[0] + r[1] + r[2] + r[3];
}

// ---------------------------------------------------------------------------
// in-place row softmax over 2048 bf16 scores; one block per row
// ---------------------------------------------------------------------------
__global__ __launch_bounds__(256) void softmax_rows(unsigned short* __restrict__ S)
{
    const long base = (long)blockIdx.x * SEQ + threadIdx.x * 8;
    const int lane = threadIdx.x & 63, wave = threadIdx.x >> 6;
    __shared__ float rbuf[8];

    short8 v = *(const short8*)(S + base);
    float x[8];
#pragma unroll
    for (int j = 0; j < 8; ++j) x[j] = bf16_to_f32((unsigned short)v[j]);

    float m = x[0];
#pragma unroll
    for (int j = 1; j < 8; ++j) m = fmaxf(m, x[j]);
    for (int o = 32; o; o >>= 1) m = fmaxf(m, __shfl_xor(m, o));
    if (lane == 0) rbuf[wave] = m;
    __syncthreads();
    m = fmaxf(fmaxf(rbuf[0], rbuf[1]), fmaxf(rbuf[2], rbuf[3]));

    float e[8], s = 0.f;
#pragma unroll
    for (int j = 0; j < 8; ++j) { e[j] = __expf(x[j] - m); s += e[j]; }
    for (int o = 32; o; o >>= 1) s += __shfl_xor(s, o);
    if (lane == 0) rbuf[4 + wave] = s;
    __syncthreads();
    s = rbuf[4] + rbuf[5] + rbuf[6] + rbuf[7];
    const float inv = 1.0f / s;

    short8 o8;
#pragma unroll
    for (int j = 0; j < 8; ++j) o8[j] = (short)f32_to_bf16(e[j] * inv);
    *(short8*)(S + base) = o8;
}

// ---------------------------------------------------------------------------
// rows with mask<=0.5: out[b,i,:] = mavg[b,:]/count[b]  (exact fp32 path)
// ---------------------------------------------------------------------------
__global__ __launch_bounds__(256) void overwrite_masked(
    float* __restrict__ out, const float* __restrict__ mask,
    const float* __restrict__ mavg, const int* __restrict__ counts)
{
    const int bid = blockIdx.x;            // b*SEQ + i
    const int b = bid >> 11;
    if (mask[bid] > 0.5f) return;
    const float inv = 1.0f / (float)counts[b];
    const long obase = (long)bid * DIM;
    const float* mv = mavg + b * DIM;
    for (int d = threadIdx.x; d < DIM; d += 256)
        out[obase + d] = mv[d] * inv;
}

extern "C" void kernel_launch(void* const* d_in, const int* in_sizes, int n_in,
                              void* d_out, int out_size, void* d_ws, size_t ws_size,
                              hipStream_t stream) {
    (void)in_sizes; (void)n_in; (void)out_size;
    const float* input_q = (const float*)d_in[0];
    const float* input_k = (const float*)d_in[1];
    const float* k_mask  = (const float*)d_in[2];
    const float* Wq      = (const float*)d_in[3];
    const float* bq      = (const float*)d_in[4];
    const float* Wk      = (const float*)d_in[5];
    const float* bk      = (const float*)d_in[6];
    float* out = (float*)d_out;

    char* ws = (char*)d_ws;
    unsigned short* qb   = (unsigned short*)(ws);                 // 16384x1024 bf16 = 32MB
    unsigned short* kb   = (unsigned short*)(ws + 33554432);      // 32MB
    unsigned short* S    = (unsigned short*)(ws + 67108864);      // 8x2048x2048 bf16 = 64MB
    unsigned short* Vt   = (unsigned short*)(ws + 134217728);     // 8x1024x2048 bf16 = 32MB
    unsigned short* Wqt  = (unsigned short*)(ws + 167772160);     // 2MB
    unsigned short* Wkt  = (unsigned short*)(ws + 169869312);     // 2MB
    float*          mavg = (float*)(ws + 171966464);              // 8x1024 f32
    int*            cnts = (int*)(ws + 171999232);
    if (ws_size < 171999264) return;

    hipMemsetAsync(mavg, 0, BATCH * DIM * sizeof(float), stream);

    // B-operand prep (all GEMMs consume NxK bf16)
    transpose_cvt<<<dim3(32, 32, 1), 256, 0, stream>>>(Wq, Wqt, DIM, DIM, 0, 0);
    transpose_cvt<<<dim3(32, 32, 1), 256, 0, stream>>>(Wk, Wkt, DIM, DIM, 0, 0);
    transpose_cvt<<<dim3(32, 64, BATCH), 256, 0, stream>>>(input_k, Vt, SEQ, DIM,
                                                           (long)SEQ * DIM, (long)DIM * SEQ);
    count_masked<<<BATCH, 256, 0, stream>>>(k_mask, cnts);
    masked_sum<<<dim3(BATCH, DIM / 256, SEQ / 256), 256, 0, stream>>>(input_k, k_mask, mavg);

    // q/k projections: (16384x1024 f32) @ W + b -> bf16
    gemm_bt<true, true, true><<<dim3(128, 8, 1), 256, 0, stream>>>(
        input_q, Wqt, qb, bq, 16384, DIM, DIM, 0, 0, 0, 1.0f);
    gemm_bt<true, true, true><<<dim3(128, 8, 1), 256, 0, stream>>>(
        input_k, Wkt, kb, bk, 16384, DIM, DIM, 0, 0, 0, 1.0f);

    // scores: per batch S = q @ k^T / 32 -> bf16
    gemm_bt<false, true, false><<<dim3(16, 16, BATCH), 256, 0, stream>>>(
        qb, kb, S, nullptr, SEQ, SEQ, DIM,
        (long)SEQ * DIM, (long)SEQ * DIM, (long)SEQ * SEQ, 0.03125f);

    softmax_rows<<<BATCH * SEQ, 256, 0, stream>>>(S);

    // out: per batch P @ V  (Bt = V^T) -> fp32
    gemm_bt<false, false, false><<<dim3(16, 8, BATCH), 256, 0, stream>>>(
        S, Vt, out, nullptr, SEQ, DIM, SEQ,
        (long)SEQ * SEQ, (long)DIM * SEQ, (long)SEQ * DIM, 1.0f);

    overwrite_masked<<<BATCH * SEQ, 256, 0, stream>>>(out, k_mask, mavg, cnts);
}

// Round 2
// 531.652 us; speedup vs baseline: 1.1449x; 1.1449x over previous
//
#include <hip/hip_runtime.h>

#define BATCH 8
#define SEQ   2048
#define DIM   1024   // D == H == 1024

typedef __attribute__((ext_vector_type(8)))  short short8;
typedef __attribute__((ext_vector_type(4)))  float floatx4;
typedef __attribute__((ext_vector_type(16))) float floatx16;

__device__ __forceinline__ unsigned short f32_to_bf16(float f) {
    union { float f; unsigned int u; } x; x.f = f;
    unsigned int r = x.u + 0x7fffu + ((x.u >> 16) & 1u);
    return (unsigned short)(r >> 16);
}

__device__ __forceinline__ float bf16_to_f32(unsigned short h) {
    union { unsigned int u; float f; } x; x.u = ((unsigned int)h) << 16;
    return x.f;
}

// async 16B/lane global->LDS. LDS base wave-uniform; HW scatters lane i at base+16*i.
__device__ __forceinline__ void async_load16(const void* g, void* l) {
    __builtin_amdgcn_global_load_lds(
        (const __attribute__((address_space(1))) void*)g,
        (__attribute__((address_space(3))) void*)l, 16, 0, 0);
}

// ---------------------------------------------------------------------------
// f32 -> bf16 bulk convert, 8 elems/thread
// ---------------------------------------------------------------------------
__global__ __launch_bounds__(256) void cvt_bf16(
    const float* __restrict__ src, unsigned short* __restrict__ dst)
{
    const long i = ((long)blockIdx.x * 256 + threadIdx.x) * 8;
    floatx4 v0 = *(const floatx4*)(src + i);
    floatx4 v1 = *(const floatx4*)(src + i + 4);
    short8 w;
#pragma unroll
    for (int j = 0; j < 4; ++j) w[j]     = (short)f32_to_bf16(v0[j]);
#pragma unroll
    for (int j = 0; j < 4; ++j) w[4 + j] = (short)f32_to_bf16(v1[j]);
    *(short8*)(dst + i) = w;
}

// ---------------------------------------------------------------------------
// C = A @ B^T (+bias) * scale.  A: MxK bf16, Bt: NxK bf16, C: MxN (bf16|f32).
// 128x128 block tile, BK=64, 256 threads (4 waves 2x2), each wave 64x64 via
// 2x2 v_mfma_f32_32x32x16_bf16.  XOR-swizzled LDS: 16B chunk q of row r lives
// at slot q^(r&7) -> conflict-free ds_read_b128 fragment loads.
// M,N multiples of 128; K multiple of 64.
// ---------------------------------------------------------------------------
template<bool C_BF16, bool BIAS>
__global__ __launch_bounds__(256) void gemm_bt(
    const unsigned short* __restrict__ A, const unsigned short* __restrict__ Bt,
    void* __restrict__ Cp, const float* __restrict__ bias,
    int N, int K, long sA, long sB, long sC, float scale)
{
    __shared__ unsigned short As[128 * 64];
    __shared__ unsigned short Bs[128 * 64];

    const int tid  = threadIdx.x;
    const int lane = tid & 63;
    const int wave = tid >> 6;
    const int wm   = wave >> 1;       // 0..1
    const int wn   = wave & 1;        // 0..1
    const int l31  = lane & 31;
    const int half = lane >> 5;       // 0..1
    const int x7   = lane & 7;
    const int row0 = blockIdx.x * 128;
    const int col0 = blockIdx.y * 128;
    const long zA = (long)blockIdx.z * sA;
    const long zB = (long)blockIdx.z * sB;
    const long zC = (long)blockIdx.z * sC;

    // staging: one async chunk = 1KB = 8 rows x 128B. lane i -> row sr=i>>3,
    // LDS slot i&7; global k-chunk sq = (i&7)^sr (XOR swizzle, in shorts*8)
    const int sr = lane >> 3;                  // 0..7
    const int sq = ((lane & 7) ^ sr) * 8;      // shorts

    const unsigned short* Abase = A  + zA + (long)row0 * K;
    const unsigned short* Bbase = Bt + zB + (long)col0 * K;
    const unsigned short* aptr[4];
    const unsigned short* bptr[4];
#pragma unroll
    for (int c = 0; c < 4; ++c) {
        const int r = (wave * 4 + c) * 8 + sr;   // 0..127
        aptr[c] = Abase + (long)r * K + sq;
        bptr[c] = Bbase + (long)r * K + sq;
    }

    floatx16 acc[2][2];
#pragma unroll
    for (int a = 0; a < 2; ++a)
#pragma unroll
        for (int b = 0; b < 2; ++b)
#pragma unroll
            for (int r = 0; r < 16; ++r) acc[a][b][r] = 0.f;

    // fragment row bases (shorts): row stride 64
    const int raf[2] = { (wm * 64 +  0 + l31) * 64, (wm * 64 + 32 + l31) * 64 };
    const int rbf[2] = { (wn * 64 +  0 + l31) * 64, (wn * 64 + 32 + l31) * 64 };

    for (int kt = 0; kt < K; kt += 64) {
#pragma unroll
        for (int c = 0; c < 4; ++c) {
            const int chunk = wave * 4 + c;
            async_load16(aptr[c] + kt, As + chunk * 512);
            async_load16(bptr[c] + kt, Bs + chunk * 512);
        }
        __syncthreads();

#pragma unroll
        for (int ks = 0; ks < 4; ++ks) {
            const int sw = ((ks * 2 + half) ^ x7) << 3;   // swizzled 16B slot (shorts)
            short8 af[2], bf[2];
#pragma unroll
            for (int t = 0; t < 2; ++t) {
                af[t] = *(const short8*)(As + raf[t] + sw);
                bf[t] = *(const short8*)(Bs + rbf[t] + sw);
            }
#pragma unroll
            for (int tm = 0; tm < 2; ++tm)
#pragma unroll
                for (int tn = 0; tn < 2; ++tn)
                    acc[tm][tn] = __builtin_amdgcn_mfma_f32_32x32x16_bf16(
                        af[tm], bf[tn], acc[tm][tn], 0, 0, 0);
        }
        __syncthreads();
    }

    // epilogue: 32x32 C/D layout col=lane&31, row=(reg&3)+8*(reg>>2)+4*(lane>>5)
#pragma unroll
    for (int tn = 0; tn < 2; ++tn) {
        const int ccol = col0 + wn * 64 + tn * 32 + l31;
        float bv = 0.f;
        if (BIAS) bv = bias[ccol];
#pragma unroll
        for (int tm = 0; tm < 2; ++tm) {
            const int rbase = row0 + wm * 64 + tm * 32 + 4 * half;
#pragma unroll
            for (int r = 0; r < 16; ++r) {
                const int crow = rbase + (r & 3) + 8 * (r >> 2);
                float v = acc[tm][tn][r] * scale + bv;
                const long ci = zC + (long)crow * N + ccol;
                if (C_BF16) ((unsigned short*)Cp)[ci] = f32_to_bf16(v);
                else        ((float*)Cp)[ci] = v;
            }
        }
    }
}

// ---------------------------------------------------------------------------
// transpose + f32->bf16:  src R x C (row-major, f32) -> dst C x R (bf16)
// ---------------------------------------------------------------------------
__global__ __launch_bounds__(256) void transpose_cvt(
    const float* __restrict__ src, unsigned short* __restrict__ dst,
    int R, int C, long sstride, long dstride)
{
    __shared__ float tile[32][33];
    const long sbase = (long)blockIdx.z * sstride;
    const long dbase = (long)blockIdx.z * dstride;
    const int c0 = blockIdx.x * 32;
    const int r0 = blockIdx.y * 32;
    const int tx = threadIdx.x & 31, ty = threadIdx.x >> 5;   // ty 0..7
#pragma unroll
    for (int i = 0; i < 32; i += 8)
        tile[ty + i][tx] = src[sbase + (long)(r0 + ty + i) * C + c0 + tx];
    __syncthreads();
#pragma unroll
    for (int i = 0; i < 32; i += 8)
        dst[dbase + (long)(c0 + ty + i) * R + r0 + tx] = f32_to_bf16(tile[tx][ty + i]);
}

// ---------------------------------------------------------------------------
// per-batch sum of input_k rows where mask <= 0.5 (atomic partial sums)
// ---------------------------------------------------------------------------
__global__ __launch_bounds__(256) void masked_sum(
    const float* __restrict__ xk, const float* __restrict__ mask, float* __restrict__ mavg)
{
    const int b = blockIdx.x;
    const int d = blockIdx.y * 256 + threadIdx.x;
    const int j0 = blockIdx.z * 256;
    const float* xb = xk + (long)b * SEQ * DIM;
    const float* mb = mask + b * SEQ;
    float s = 0.f;
    for (int j = j0; j < j0 + 256; ++j) {
        float mv = mb[j];
        float v  = xb[(long)j * DIM + d];
        s += (mv <= 0.5f) ? v : 0.f;
    }
    atomicAdd(&mavg[b * DIM + d], s);
}

__global__ __launch_bounds__(256) void count_masked(const float* __restrict__ mask, int* __restrict__ counts)
{
    const int b = blockIdx.x;
    int c = 0;
    for (int j = threadIdx.x; j < SEQ; j += 256) c += (mask[b * SEQ + j] <= 0.5f) ? 1 : 0;
    for (int o = 32; o; o >>= 1) c += __shfl_xor(c, o);
    __shared__ int r[4];
    if ((threadIdx.x & 63) == 0) r[threadIdx.x >> 6] = c;
    __syncthreads();
    if (threadIdx.x == 0) counts[b] = r[0] + r[1] + r[2] + r[3];
}

// ---------------------------------------------------------------------------
// in-place row softmax over 2048 bf16 scores; one block per row
// ---------------------------------------------------------------------------
__global__ __launch_bounds__(256) void softmax_rows(unsigned short* __restrict__ S)
{
    const long base = (long)blockIdx.x * SEQ + threadIdx.x * 8;
    const int lane = threadIdx.x & 63, wave = threadIdx.x >> 6;
    __shared__ float rbuf[8];

    short8 v = *(const short8*)(S + base);
    float x[8];
#pragma unroll
    for (int j = 0; j < 8; ++j) x[j] = bf16_to_f32((unsigned short)v[j]);

    float m = x[0];
#pragma unroll
    for (int j = 1; j < 8; ++j) m = fmaxf(m, x[j]);
    for (int o = 32; o; o >>= 1) m = fmaxf(m, __shfl_xor(m, o));
    if (lane == 0) rbuf[wave] = m;
    __syncthreads();
    m = fmaxf(fmaxf(rbuf[0], rbuf[1]), fmaxf(rbuf[2], rbuf[3]));

    float e[8], s = 0.f;
#pragma unroll
    for (int j = 0; j < 8; ++j) { e[j] = __expf(x[j] - m); s += e[j]; }
    for (int o = 32; o; o >>= 1) s += __shfl_xor(s, o);
    if (lane == 0) rbuf[4 + wave] = s;
    __syncthreads();
    s = rbuf[4] + rbuf[5] + rbuf[6] + rbuf[7];
    const float inv = 1.0f / s;

    short8 o8;
#pragma unroll
    for (int j = 0; j < 8; ++j) o8[j] = (short)f32_to_bf16(e[j] * inv);
    *(short8*)(S + base) = o8;
}

// ---------------------------------------------------------------------------
// rows with mask<=0.5: out[b,i,:] = mavg[b,:]/count[b]  (exact fp32 path)
// ---------------------------------------------------------------------------
__global__ __launch_bounds__(256) void overwrite_masked(
    float* __restrict__ out, const float* __restrict__ mask,
    const float* __restrict__ mavg, const int* __restrict__ counts)
{
    const int bid = blockIdx.x;            // b*SEQ + i
    const int b = bid >> 11;
    if (mask[bid] > 0.5f) return;
    const float inv = 1.0f / (float)counts[b];
    const long obase = (long)bid * DIM;
    const float* mv = mavg + b * DIM;
    for (int d = threadIdx.x; d < DIM; d += 256)
        out[obase + d] = mv[d] * inv;
}

extern "C" void kernel_launch(void* const* d_in, const int* in_sizes, int n_in,
                              void* d_out, int out_size, void* d_ws, size_t ws_size,
                              hipStream_t stream) {
    (void)in_sizes; (void)n_in; (void)out_size;
    const float* input_q = (const float*)d_in[0];
    const float* input_k = (const float*)d_in[1];
    const float* k_mask  = (const float*)d_in[2];
    const float* Wq      = (const float*)d_in[3];
    const float* bq      = (const float*)d_in[4];
    const float* Wk      = (const float*)d_in[5];
    const float* bk      = (const float*)d_in[6];
    float* out = (float*)d_out;

    // Workspace map (bytes). qbf/kbf alias S: both are dead once the
    // projections have consumed them, before the scores GEMM writes S.
    char* ws = (char*)d_ws;
    unsigned short* qbf  = (unsigned short*)(ws);                 // 32MB (aliases S lo)
    unsigned short* kbf  = (unsigned short*)(ws + 33554432);      // 32MB (aliases S hi)
    unsigned short* S    = (unsigned short*)(ws);                 // 8x2048x2048 bf16 = 64MB
    unsigned short* qb   = (unsigned short*)(ws + 67108864);      // 32MB
    unsigned short* kb   = (unsigned short*)(ws + 100663296);     // 32MB
    unsigned short* Vt   = (unsigned short*)(ws + 134217728);     // 32MB
    unsigned short* Wqt  = (unsigned short*)(ws + 167772160);     // 2MB
    unsigned short* Wkt  = (unsigned short*)(ws + 169869312);     // 2MB
    float*          mavg = (float*)(ws + 171966464);              // 8x1024 f32
    int*            cnts = (int*)(ws + 171999232);
    if (ws_size < 171999264) return;

    hipMemsetAsync(mavg, 0, BATCH * DIM * sizeof(float), stream);

    // input conversions + B-operand prep (all GEMMs consume bf16 A + NxK bf16 B)
    cvt_bf16<<<8192, 256, 0, stream>>>(input_q, qbf);
    cvt_bf16<<<8192, 256, 0, stream>>>(input_k, kbf);
    transpose_cvt<<<dim3(32, 32, 1), 256, 0, stream>>>(Wq, Wqt, DIM, DIM, 0, 0);
    transpose_cvt<<<dim3(32, 32, 1), 256, 0, stream>>>(Wk, Wkt, DIM, DIM, 0, 0);
    transpose_cvt<<<dim3(32, 64, BATCH), 256, 0, stream>>>(input_k, Vt, SEQ, DIM,
                                                           (long)SEQ * DIM, (long)DIM * SEQ);
    count_masked<<<BATCH, 256, 0, stream>>>(k_mask, cnts);
    masked_sum<<<dim3(BATCH, DIM / 256, SEQ / 256), 256, 0, stream>>>(input_k, k_mask, mavg);

    // q/k projections: (16384x1024 bf16) @ W^T + b -> bf16
    gemm_bt<true, true><<<dim3(128, 8, 1), 256, 0, stream>>>(
        qbf, Wqt, qb, bq, DIM, DIM, 0, 0, 0, 1.0f);
    gemm_bt<true, true><<<dim3(128, 8, 1), 256, 0, stream>>>(
        kbf, Wkt, kb, bk, DIM, DIM, 0, 0, 0, 1.0f);

    // scores: per batch S = q @ k^T / 32 -> bf16 (overwrites qbf/kbf region)
    gemm_bt<true, false><<<dim3(16, 16, BATCH), 256, 0, stream>>>(
        qb, kb, S, nullptr, SEQ, DIM,
        (long)SEQ * DIM, (long)SEQ * DIM, (long)SEQ * SEQ, 0.03125f);

    softmax_rows<<<BATCH * SEQ, 256, 0, stream>>>(S);

    // out: per batch P @ V  (Bt = V^T) -> fp32
    gemm_bt<false, false><<<dim3(16, 8, BATCH), 256, 0, stream>>>(
        S, Vt, out, nullptr, DIM, SEQ,
        (long)SEQ * SEQ, (long)DIM * SEQ, (long)SEQ * DIM, 1.0f);

    overwrite_masked<<<BATCH * SEQ, 256, 0, stream>>>(out, k_mask, mavg, cnts);
}

// Round 3
// 510.032 us; speedup vs baseline: 1.1935x; 1.0424x over previous
//
#include <hip/hip_runtime.h>

#define BATCH 8
#define SEQ   2048
#define DIM   1024   // D == H == 1024

typedef __attribute__((ext_vector_type(8)))  short short8;
typedef __attribute__((ext_vector_type(4)))  short short4v;
typedef __attribute__((ext_vector_type(4)))  float floatx4;
typedef __attribute__((ext_vector_type(16))) float floatx16;

__device__ __forceinline__ unsigned short f32_to_bf16(float f) {
    union { float f; unsigned int u; } x; x.f = f;
    unsigned int r = x.u + 0x7fffu + ((x.u >> 16) & 1u);
    return (unsigned short)(r >> 16);
}

__device__ __forceinline__ float bf16_to_f32(unsigned short h) {
    union { unsigned int u; float f; } x; x.u = ((unsigned int)h) << 16;
    return x.f;
}

// async 16B/lane global->LDS. LDS base wave-uniform; HW scatters lane i at base+16*i.
__device__ __forceinline__ void async_load16(const void* g, void* l) {
    __builtin_amdgcn_global_load_lds(
        (const __attribute__((address_space(1))) void*)g,
        (__attribute__((address_space(3))) void*)l, 16, 0, 0);
}

// ---------------------------------------------------------------------------
// per-batch compaction: idx[b][0..cnt) = rows with mask>0.5 (ascending),
// pads idx[cnt..SEQ) = 0; cnt[b]; padcnt[b] = round-up-128(cnt).
// ---------------------------------------------------------------------------
__global__ __launch_bounds__(256) void build_idx(
    const float* __restrict__ mask, int* __restrict__ idx,
    int* __restrict__ cnt, int* __restrict__ padcnt)
{
    const int b = blockIdx.x;
    const int t = threadIdx.x;
    const float* mb = mask + b * SEQ;
    int flags[8]; int c = 0;
#pragma unroll
    for (int j = 0; j < 8; ++j) {
        flags[j] = (mb[t * 8 + j] > 0.5f) ? 1 : 0;
        c += flags[j];
    }
    int sc = c;                       // inclusive scan within wave
    for (int o = 1; o < 64; o <<= 1) {
        int v = __shfl_up(sc, o);
        if ((t & 63) >= o) sc += v;
    }
    __shared__ int wtot[4];
    const int lane = t & 63, wave = t >> 6;
    if (lane == 63) wtot[wave] = sc;
    __syncthreads();
    int woff = 0;
    for (int w = 0; w < wave; ++w) woff += wtot[w];
    int p = woff + sc - c;            // exclusive offset
#pragma unroll
    for (int j = 0; j < 8; ++j)
        if (flags[j]) idx[b * SEQ + (p++)] = t * 8 + j;
    __syncthreads();
    const int total = wtot[0] + wtot[1] + wtot[2] + wtot[3];
    if (t == 0) { cnt[b] = total; padcnt[b] = (total + 127) & ~127; }
    for (int q = total + t; q < SEQ; q += 256) idx[b * SEQ + q] = 0;
}

// ---------------------------------------------------------------------------
// gather unmasked input_q rows (f32) -> compacted bf16 rows
// grid (SEQ, BATCH), block 256 (4 elems/thread)
// ---------------------------------------------------------------------------
__global__ __launch_bounds__(256) void gather_cvt_q(
    const float* __restrict__ xq, const int* __restrict__ idx,
    const int* __restrict__ padcnt, unsigned short* __restrict__ qc)
{
    const int b = blockIdx.y;
    const int rc = blockIdx.x;
    if (rc >= padcnt[b]) return;
    const int src = idx[b * SEQ + rc];
    const float* s = xq + ((long)b * SEQ + src) * DIM + threadIdx.x * 4;
    unsigned short* d = qc + ((long)b * SEQ + rc) * DIM + threadIdx.x * 4;
    floatx4 v = *(const floatx4*)s;
    short4v w;
#pragma unroll
    for (int j = 0; j < 4; ++j) w[j] = (short)f32_to_bf16(v[j]);
    *(short4v*)d = w;
}

// ---------------------------------------------------------------------------
// f32 -> bf16 bulk convert, 8 elems/thread
// ---------------------------------------------------------------------------
__global__ __launch_bounds__(256) void cvt_bf16(
    const float* __restrict__ src, unsigned short* __restrict__ dst)
{
    const long i = ((long)blockIdx.x * 256 + threadIdx.x) * 8;
    floatx4 v0 = *(const floatx4*)(src + i);
    floatx4 v1 = *(const floatx4*)(src + i + 4);
    short8 w;
#pragma unroll
    for (int j = 0; j < 4; ++j) w[j]     = (short)f32_to_bf16(v0[j]);
#pragma unroll
    for (int j = 0; j < 4; ++j) w[4 + j] = (short)f32_to_bf16(v1[j]);
    *(short8*)(dst + i) = w;
}

// ---------------------------------------------------------------------------
// C = A @ B^T (+bias) * scale.  A: MxK bf16, Bt: NxK bf16, C: MxN (bf16|f32).
// 128x128 block tile, BK=64, 256 threads (4 waves 2x2), each wave 64x64 via
// 2x2 v_mfma_f32_32x32x16_bf16.  XOR-swizzled LDS staging.
// LIMIT: skip row-blocks past mlim[z] (padded compacted row count).
// SCATTER: epilogue maps compacted row -> idx[z][row], skips rows >= cnt[z].
// ---------------------------------------------------------------------------
template<bool C_BF16, bool BIAS, bool LIMIT, bool SCATTER>
__global__ __launch_bounds__(256) void gemm_bt(
    const unsigned short* __restrict__ A, const unsigned short* __restrict__ Bt,
    void* __restrict__ Cp, const float* __restrict__ bias,
    int N, int K, long sA, long sB, long sC, float scale,
    const int* __restrict__ mlim, const int* __restrict__ cntp,
    const int* __restrict__ idx)
{
    const int row0 = blockIdx.x * 128;
    if (LIMIT && row0 >= mlim[blockIdx.z]) return;

    __shared__ unsigned short As[128 * 64];
    __shared__ unsigned short Bs[128 * 64];

    const int tid  = threadIdx.x;
    const int lane = tid & 63;
    const int wave = tid >> 6;
    const int wm   = wave >> 1;       // 0..1
    const int wn   = wave & 1;        // 0..1
    const int l31  = lane & 31;
    const int half = lane >> 5;       // 0..1
    const int x7   = lane & 7;
    const int col0 = blockIdx.y * 128;
    const long zA = (long)blockIdx.z * sA;
    const long zB = (long)blockIdx.z * sB;
    const long zC = (long)blockIdx.z * sC;

    // staging: one async chunk = 1KB = 8 rows x 128B. lane i -> row sr=i>>3,
    // LDS slot i&7; global k-chunk sq = (i&7)^sr (XOR swizzle, in shorts*8)
    const int sr = lane >> 3;                  // 0..7
    const int sq = ((lane & 7) ^ sr) * 8;      // shorts

    const unsigned short* Abase = A  + zA + (long)row0 * K;
    const unsigned short* Bbase = Bt + zB + (long)col0 * K;
    const unsigned short* aptr[4];
    const unsigned short* bptr[4];
#pragma unroll
    for (int c = 0; c < 4; ++c) {
        const int r = (wave * 4 + c) * 8 + sr;   // 0..127
        aptr[c] = Abase + (long)r * K + sq;
        bptr[c] = Bbase + (long)r * K + sq;
    }

    floatx16 acc[2][2];
#pragma unroll
    for (int a = 0; a < 2; ++a)
#pragma unroll
        for (int b = 0; b < 2; ++b)
#pragma unroll
            for (int r = 0; r < 16; ++r) acc[a][b][r] = 0.f;

    // fragment row bases (shorts): row stride 64
    const int raf[2] = { (wm * 64 +  0 + l31) * 64, (wm * 64 + 32 + l31) * 64 };
    const int rbf[2] = { (wn * 64 +  0 + l31) * 64, (wn * 64 + 32 + l31) * 64 };

    for (int kt = 0; kt < K; kt += 64) {
#pragma unroll
        for (int c = 0; c < 4; ++c) {
            const int chunk = wave * 4 + c;
            async_load16(aptr[c] + kt, As + chunk * 512);
            async_load16(bptr[c] + kt, Bs + chunk * 512);
        }
        __syncthreads();

#pragma unroll
        for (int ks = 0; ks < 4; ++ks) {
            const int sw = ((ks * 2 + half) ^ x7) << 3;   // swizzled 16B slot (shorts)
            short8 af[2], bf[2];
#pragma unroll
            for (int t = 0; t < 2; ++t) {
                af[t] = *(const short8*)(As + raf[t] + sw);
                bf[t] = *(const short8*)(Bs + rbf[t] + sw);
            }
#pragma unroll
            for (int tm = 0; tm < 2; ++tm)
#pragma unroll
                for (int tn = 0; tn < 2; ++tn)
                    acc[tm][tn] = __builtin_amdgcn_mfma_f32_32x32x16_bf16(
                        af[tm], bf[tn], acc[tm][tn], 0, 0, 0);
        }
        __syncthreads();
    }

    // epilogue: 32x32 C/D layout col=lane&31, row=(reg&3)+8*(reg>>2)+4*(lane>>5)
    const int climit = SCATTER ? cntp[blockIdx.z] : 0;
    const int* ridx  = SCATTER ? (idx + blockIdx.z * SEQ) : (const int*)nullptr;
#pragma unroll
    for (int tn = 0; tn < 2; ++tn) {
        const int ccol = col0 + wn * 64 + tn * 32 + l31;
        float bv = 0.f;
        if (BIAS) bv = bias[ccol];
#pragma unroll
        for (int tm = 0; tm < 2; ++tm) {
            const int rbase = row0 + wm * 64 + tm * 32 + 4 * half;
#pragma unroll
            for (int r = 0; r < 16; ++r) {
                const int crow = rbase + (r & 3) + 8 * (r >> 2);
                float v = acc[tm][tn][r] * scale + bv;
                long orow = crow;
                if (SCATTER) {
                    if (crow >= climit) continue;
                    orow = ridx[crow];
                }
                const long ci = zC + orow * (long)N + ccol;
                if (C_BF16) ((unsigned short*)Cp)[ci] = f32_to_bf16(v);
                else        ((float*)Cp)[ci] = v;
            }
        }
    }
}

// ---------------------------------------------------------------------------
// transpose + f32->bf16:  src R x C (row-major, f32) -> dst C x R (bf16)
// ---------------------------------------------------------------------------
__global__ __launch_bounds__(256) void transpose_cvt(
    const float* __restrict__ src, unsigned short* __restrict__ dst,
    int R, int C, long sstride, long dstride)
{
    __shared__ float tile[32][33];
    const long sbase = (long)blockIdx.z * sstride;
    const long dbase = (long)blockIdx.z * dstride;
    const int c0 = blockIdx.x * 32;
    const int r0 = blockIdx.y * 32;
    const int tx = threadIdx.x & 31, ty = threadIdx.x >> 5;   // ty 0..7
#pragma unroll
    for (int i = 0; i < 32; i += 8)
        tile[ty + i][tx] = src[sbase + (long)(r0 + ty + i) * C + c0 + tx];
    __syncthreads();
#pragma unroll
    for (int i = 0; i < 32; i += 8)
        dst[dbase + (long)(c0 + ty + i) * R + r0 + tx] = f32_to_bf16(tile[tx][ty + i]);
}

// ---------------------------------------------------------------------------
// per-batch sum of input_k rows where mask <= 0.5 (atomic partial sums)
// ---------------------------------------------------------------------------
__global__ __launch_bounds__(256) void masked_sum(
    const float* __restrict__ xk, const float* __restrict__ mask, float* __restrict__ mavg)
{
    const int b = blockIdx.x;
    const int d = blockIdx.y * 256 + threadIdx.x;
    const int j0 = blockIdx.z * 256;
    const float* xb = xk + (long)b * SEQ * DIM;
    const float* mb = mask + b * SEQ;
    float s = 0.f;
    for (int j = j0; j < j0 + 256; ++j) {
        float mv = mb[j];
        float v  = xb[(long)j * DIM + d];
        s += (mv <= 0.5f) ? v : 0.f;
    }
    atomicAdd(&mavg[b * DIM + d], s);
}

// ---------------------------------------------------------------------------
// in-place row softmax over 2048 bf16 scores; one block per compacted row
// ---------------------------------------------------------------------------
__global__ __launch_bounds__(256) void softmax_rows(
    unsigned short* __restrict__ S, const int* __restrict__ padcnt)
{
    const int b = blockIdx.x >> 11, rc = blockIdx.x & 2047;
    if (rc >= padcnt[b]) return;
    const long base = (long)blockIdx.x * SEQ + threadIdx.x * 8;
    const int lane = threadIdx.x & 63, wave = threadIdx.x >> 6;
    __shared__ float rbuf[8];

    short8 v = *(const short8*)(S + base);
    float x[8];
#pragma unroll
    for (int j = 0; j < 8; ++j) x[j] = bf16_to_f32((unsigned short)v[j]);

    float m = x[0];
#pragma unroll
    for (int j = 1; j < 8; ++j) m = fmaxf(m, x[j]);
    for (int o = 32; o; o >>= 1) m = fmaxf(m, __shfl_xor(m, o));
    if (lane == 0) rbuf[wave] = m;
    __syncthreads();
    m = fmaxf(fmaxf(rbuf[0], rbuf[1]), fmaxf(rbuf[2], rbuf[3]));

    float e[8], s = 0.f;
#pragma unroll
    for (int j = 0; j < 8; ++j) { e[j] = __expf(x[j] - m); s += e[j]; }
    for (int o = 32; o; o >>= 1) s += __shfl_xor(s, o);
    if (lane == 0) rbuf[4 + wave] = s;
    __syncthreads();
    s = rbuf[4] + rbuf[5] + rbuf[6] + rbuf[7];
    const float inv = 1.0f / s;

    short8 o8;
#pragma unroll
    for (int j = 0; j < 8; ++j) o8[j] = (short)f32_to_bf16(e[j] * inv);
    *(short8*)(S + base) = o8;
}

// ---------------------------------------------------------------------------
// rows with mask<=0.5: out[b,i,:] = mavg[b,:]/masked_count  (exact fp32 path)
// ---------------------------------------------------------------------------
__global__ __launch_bounds__(256) void overwrite_masked(
    float* __restrict__ out, const float* __restrict__ mask,
    const float* __restrict__ mavg, const int* __restrict__ cnt)
{
    const int bid = blockIdx.x;            // b*SEQ + i
    const int b = bid >> 11;
    if (mask[bid] > 0.5f) return;
    const float inv = 1.0f / (float)(SEQ - cnt[b]);
    const long obase = (long)bid * DIM;
    const float* mv = mavg + b * DIM;
    for (int d = threadIdx.x; d < DIM; d += 256)
        out[obase + d] = mv[d] * inv;
}

extern "C" void kernel_launch(void* const* d_in, const int* in_sizes, int n_in,
                              void* d_out, int out_size, void* d_ws, size_t ws_size,
                              hipStream_t stream) {
    (void)in_sizes; (void)n_in; (void)out_size;
    const float* input_q = (const float*)d_in[0];
    const float* input_k = (const float*)d_in[1];
    const float* k_mask  = (const float*)d_in[2];
    const float* Wq      = (const float*)d_in[3];
    const float* bq      = (const float*)d_in[4];
    const float* Wk      = (const float*)d_in[5];
    const float* bk      = (const float*)d_in[6];
    float* out = (float*)d_out;

    // Workspace map. qc/kbf alias S (dead before scores GEMM writes S).
    char* ws = (char*)d_ws;
    unsigned short* qc   = (unsigned short*)(ws);                 // 32MB (aliases S lo)
    unsigned short* kbf  = (unsigned short*)(ws + 33554432);      // 32MB (aliases S hi)
    unsigned short* S    = (unsigned short*)(ws);                 // 64MB
    unsigned short* qp   = (unsigned short*)(ws + 67108864);      // 32MB
    unsigned short* kb   = (unsigned short*)(ws + 100663296);     // 32MB
    unsigned short* Vt   = (unsigned short*)(ws + 134217728);     // 32MB
    unsigned short* Wqt  = (unsigned short*)(ws + 167772160);     // 2MB
    unsigned short* Wkt  = (unsigned short*)(ws + 169869312);     // 2MB
    float*          mavg = (float*)(ws + 171966464);              // 32KB
    int*            idx  = (int*)(ws + 171999232);                // 64KB
    int*            cnts = (int*)(ws + 172064768);                // 32B
    int*            pcnt = (int*)(ws + 172064800);                // 32B
    if (ws_size < 172064832) return;

    hipMemsetAsync(mavg, 0, BATCH * DIM * sizeof(float), stream);

    build_idx<<<BATCH, 256, 0, stream>>>(k_mask, idx, cnts, pcnt);
    gather_cvt_q<<<dim3(SEQ, BATCH), 256, 0, stream>>>(input_q, idx, pcnt, qc);
    cvt_bf16<<<8192, 256, 0, stream>>>(input_k, kbf);
    transpose_cvt<<<dim3(32, 32, 1), 256, 0, stream>>>(Wq, Wqt, DIM, DIM, 0, 0);
    transpose_cvt<<<dim3(32, 32, 1), 256, 0, stream>>>(Wk, Wkt, DIM, DIM, 0, 0);
    transpose_cvt<<<dim3(32, 64, BATCH), 256, 0, stream>>>(input_k, Vt, SEQ, DIM,
                                                           (long)SEQ * DIM, (long)DIM * SEQ);
    masked_sum<<<dim3(BATCH, DIM / 256, SEQ / 256), 256, 0, stream>>>(input_k, k_mask, mavg);

    // q projection on compacted rows: per batch (padcnt x 1024) @ Wq^T + bq
    gemm_bt<true, true, true, false><<<dim3(16, 8, BATCH), 256, 0, stream>>>(
        qc, Wqt, qp, bq, DIM, DIM,
        (long)SEQ * DIM, 0, (long)SEQ * DIM, 1.0f, pcnt, nullptr, nullptr);
    // k projection, full 16384 rows flat
    gemm_bt<true, true, false, false><<<dim3(128, 8, 1), 256, 0, stream>>>(
        kbf, Wkt, kb, bk, DIM, DIM, 0, 0, 0, 1.0f, nullptr, nullptr, nullptr);

    // scores: per batch S[rc,:] = qp[rc] @ k^T / 32 -> bf16 (compacted rows)
    gemm_bt<true, false, true, false><<<dim3(16, 16, BATCH), 256, 0, stream>>>(
        qp, kb, S, nullptr, SEQ, DIM,
        (long)SEQ * DIM, (long)SEQ * DIM, (long)SEQ * SEQ, 0.03125f, pcnt, nullptr, nullptr);

    softmax_rows<<<BATCH * SEQ, 256, 0, stream>>>(S, pcnt);

    // out rows (scattered): per batch P @ V with row map idx
    gemm_bt<false, false, true, true><<<dim3(16, 8, BATCH), 256, 0, stream>>>(
        S, Vt, out, nullptr, DIM, SEQ,
        (long)SEQ * SEQ, (long)DIM * SEQ, (long)SEQ * DIM, 1.0f, pcnt, cnts, idx);

    overwrite_masked<<<BATCH * SEQ, 256, 0, stream>>>(out, k_mask, mavg, cnts);
}

// Round 4
// 505.377 us; speedup vs baseline: 1.2045x; 1.0092x over previous
//
#include <hip/hip_runtime.h>

#define BATCH 8
#define SEQ   2048
#define DIM   1024   // D == H == 1024

typedef __attribute__((ext_vector_type(8)))  short short8;
typedef __attribute__((ext_vector_type(4)))  short short4v;
typedef __attribute__((ext_vector_type(4)))  float floatx4;
typedef __attribute__((ext_vector_type(16))) float floatx16;

__device__ __forceinline__ unsigned short f32_to_bf16(float f) {
    union { float f; unsigned int u; } x; x.f = f;
    unsigned int r = x.u + 0x7fffu + ((x.u >> 16) & 1u);
    return (unsigned short)(r >> 16);
}

__device__ __forceinline__ float bf16_to_f32(unsigned short h) {
    union { unsigned int u; float f; } x; x.u = ((unsigned int)h) << 16;
    return x.f;
}

// async 16B/lane global->LDS. LDS base wave-uniform; HW scatters lane i at base+16*i.
__device__ __forceinline__ void async_load16(const void* g, void* l) {
    __builtin_amdgcn_global_load_lds(
        (const __attribute__((address_space(1))) void*)g,
        (__attribute__((address_space(3))) void*)l, 16, 0, 0);
}

// ---------------------------------------------------------------------------
// per-batch compaction: idx[b][0..cnt) = rows with mask>0.5 (ascending),
// pads idx[cnt..SEQ) = 0; cnt[b]; padcnt[b] = round-up-128(cnt).
// ---------------------------------------------------------------------------
__global__ __launch_bounds__(256) void build_idx(
    const float* __restrict__ mask, int* __restrict__ idx,
    int* __restrict__ cnt, int* __restrict__ padcnt)
{
    const int b = blockIdx.x;
    const int t = threadIdx.x;
    const float* mb = mask + b * SEQ;
    int flags[8]; int c = 0;
#pragma unroll
    for (int j = 0; j < 8; ++j) {
        flags[j] = (mb[t * 8 + j] > 0.5f) ? 1 : 0;
        c += flags[j];
    }
    int sc = c;                       // inclusive scan within wave
    for (int o = 1; o < 64; o <<= 1) {
        int v = __shfl_up(sc, o);
        if ((t & 63) >= o) sc += v;
    }
    __shared__ int wtot[4];
    const int lane = t & 63, wave = t >> 6;
    if (lane == 63) wtot[wave] = sc;
    __syncthreads();
    int woff = 0;
    for (int w = 0; w < wave; ++w) woff += wtot[w];
    int p = woff + sc - c;            // exclusive offset
#pragma unroll
    for (int j = 0; j < 8; ++j)
        if (flags[j]) idx[b * SEQ + (p++)] = t * 8 + j;
    __syncthreads();
    const int total = wtot[0] + wtot[1] + wtot[2] + wtot[3];
    if (t == 0) { cnt[b] = total; padcnt[b] = (total + 127) & ~127; }
    for (int q = total + t; q < SEQ; q += 256) idx[b * SEQ + q] = 0;
}

// ---------------------------------------------------------------------------
// gather unmasked input_q rows (f32) -> compacted bf16 rows
// ---------------------------------------------------------------------------
__global__ __launch_bounds__(256) void gather_cvt_q(
    const float* __restrict__ xq, const int* __restrict__ idx,
    const int* __restrict__ padcnt, unsigned short* __restrict__ qc)
{
    const int b = blockIdx.y;
    const int rc = blockIdx.x;
    if (rc >= padcnt[b]) return;
    const int src = idx[b * SEQ + rc];
    const float* s = xq + ((long)b * SEQ + src) * DIM + threadIdx.x * 4;
    unsigned short* d = qc + ((long)b * SEQ + rc) * DIM + threadIdx.x * 4;
    floatx4 v = *(const floatx4*)s;
    short4v w;
#pragma unroll
    for (int j = 0; j < 4; ++j) w[j] = (short)f32_to_bf16(v[j]);
    *(short4v*)d = w;
}

// ---------------------------------------------------------------------------
// fused: kbf = bf16(input_k)  AND  mavg += masked column partial sums.
// grid (BATCH, DIM/256, SEQ/256), block 256 (thread owns one column d).
// ---------------------------------------------------------------------------
__global__ __launch_bounds__(256) void prep_k(
    const float* __restrict__ xk, const float* __restrict__ mask,
    unsigned short* __restrict__ kbf, float* __restrict__ mavg)
{
    const int b = blockIdx.x;
    const int d = blockIdx.y * 256 + threadIdx.x;
    const int j0 = blockIdx.z * 256;
    const float* xb = xk + (long)b * SEQ * DIM;
    unsigned short* kb = kbf + (long)b * SEQ * DIM;
    const float* mb = mask + b * SEQ;
    float s = 0.f;
    for (int j = j0; j < j0 + 256; ++j) {
        float mv = mb[j];
        float v  = xb[(long)j * DIM + d];
        kb[(long)j * DIM + d] = f32_to_bf16(v);
        s += (mv <= 0.5f) ? v : 0.f;
    }
    atomicAdd(&mavg[b * DIM + d], s);
}

// ---------------------------------------------------------------------------
// C = A @ B^T (+bias) * scale.  A: MxK bf16, Bt: NxK bf16, C: MxN (bf16|f32).
// 128x128 block tile, BK=64, 256 threads (4 waves 2x2), each wave 64x64 via
// 2x2 v_mfma_f32_32x32x16_bf16.  XOR-swizzled LDS staging.
// PING-PONG double buffer: stage tile t+1 while computing tile t; ONE barrier
// per K-iter — the staging loads get the whole compute phase to land instead
// of being drained immediately (the m97 2-barrier stall).
// LIMIT: skip row-blocks past mlim[z].  SCATTER: row -> idx[z][row], < cnt[z].
// ---------------------------------------------------------------------------
template<bool C_BF16, bool BIAS, bool LIMIT, bool SCATTER>
__global__ __launch_bounds__(256) void gemm_bt(
    const unsigned short* __restrict__ A, const unsigned short* __restrict__ Bt,
    void* __restrict__ Cp, const float* __restrict__ bias,
    int N, int K, long sA, long sB, long sC, float scale,
    const int* __restrict__ mlim, const int* __restrict__ cntp,
    const int* __restrict__ idx)
{
    const int row0 = blockIdx.x * 128;
    if (LIMIT && row0 >= mlim[blockIdx.z]) return;

    __shared__ unsigned short As[2][128 * 64];   // 16 KB x2
    __shared__ unsigned short Bs[2][128 * 64];   // 16 KB x2

    const int tid  = threadIdx.x;
    const int lane = tid & 63;
    const int wave = tid >> 6;
    const int wm   = wave >> 1;       // 0..1
    const int wn   = wave & 1;        // 0..1
    const int l31  = lane & 31;
    const int half = lane >> 5;       // 0..1
    const int x7   = lane & 7;
    const int col0 = blockIdx.y * 128;
    const long zA = (long)blockIdx.z * sA;
    const long zB = (long)blockIdx.z * sB;
    const long zC = (long)blockIdx.z * sC;

    // staging: one async chunk = 1KB = 8 rows x 128B. lane i -> row sr=i>>3,
    // LDS slot i&7; global k-chunk sq = (i&7)^sr (XOR swizzle, in shorts*8)
    const int sr = lane >> 3;                  // 0..7
    const int sq = ((lane & 7) ^ sr) * 8;      // shorts

    const unsigned short* Abase = A  + zA + (long)row0 * K;
    const unsigned short* Bbase = Bt + zB + (long)col0 * K;
    const unsigned short* aptr[4];
    const unsigned short* bptr[4];
#pragma unroll
    for (int c = 0; c < 4; ++c) {
        const int r = (wave * 4 + c) * 8 + sr;   // 0..127
        aptr[c] = Abase + (long)r * K + sq;
        bptr[c] = Bbase + (long)r * K + sq;
    }

    floatx16 acc[2][2];
#pragma unroll
    for (int a = 0; a < 2; ++a)
#pragma unroll
        for (int b = 0; b < 2; ++b)
#pragma unroll
            for (int r = 0; r < 16; ++r) acc[a][b][r] = 0.f;

    // fragment row bases (shorts): row stride 64
    const int raf[2] = { (wm * 64 +  0 + l31) * 64, (wm * 64 + 32 + l31) * 64 };
    const int rbf[2] = { (wn * 64 +  0 + l31) * 64, (wn * 64 + 32 + l31) * 64 };

    const int NIT = K >> 6;

    // prologue: stage tile 0 into buffer 0
#pragma unroll
    for (int c = 0; c < 4; ++c) {
        const int chunk = wave * 4 + c;
        async_load16(aptr[c], &As[0][chunk * 512]);
        async_load16(bptr[c], &Bs[0][chunk * 512]);
    }
    __syncthreads();

    for (int it = 0; it < NIT; ++it) {
        const int buf = it & 1;
        // stage tile it+1 into the other buffer (no wait — lands during compute)
        if (it + 1 < NIT) {
            const int kn = (it + 1) << 6;
#pragma unroll
            for (int c = 0; c < 4; ++c) {
                const int chunk = wave * 4 + c;
                async_load16(aptr[c] + kn, &As[buf ^ 1][chunk * 512]);
                async_load16(bptr[c] + kn, &Bs[buf ^ 1][chunk * 512]);
            }
        }
        // compute tile it from buf
#pragma unroll
        for (int ks = 0; ks < 4; ++ks) {
            const int sw = ((ks * 2 + half) ^ x7) << 3;   // swizzled 16B slot (shorts)
            short8 af[2], bf[2];
#pragma unroll
            for (int t = 0; t < 2; ++t) {
                af[t] = *(const short8*)(&As[buf][raf[t] + sw]);
                bf[t] = *(const short8*)(&Bs[buf][rbf[t] + sw]);
            }
#pragma unroll
            for (int tm = 0; tm < 2; ++tm)
#pragma unroll
                for (int tn = 0; tn < 2; ++tn)
                    acc[tm][tn] = __builtin_amdgcn_mfma_f32_32x32x16_bf16(
                        af[tm], bf[tn], acc[tm][tn], 0, 0, 0);
        }
        __syncthreads();   // drains next-tile loads (had whole compute to land)
    }

    // epilogue: 32x32 C/D layout col=lane&31, row=(reg&3)+8*(reg>>2)+4*(lane>>5)
    const int climit = SCATTER ? cntp[blockIdx.z] : 0;
    const int* ridx  = SCATTER ? (idx + blockIdx.z * SEQ) : (const int*)nullptr;
#pragma unroll
    for (int tn = 0; tn < 2; ++tn) {
        const int ccol = col0 + wn * 64 + tn * 32 + l31;
        float bv = 0.f;
        if (BIAS) bv = bias[ccol];
#pragma unroll
        for (int tm = 0; tm < 2; ++tm) {
            const int rbase = row0 + wm * 64 + tm * 32 + 4 * half;
#pragma unroll
            for (int r = 0; r < 16; ++r) {
                const int crow = rbase + (r & 3) + 8 * (r >> 2);
                float v = acc[tm][tn][r] * scale + bv;
                long orow = crow;
                if (SCATTER) {
                    if (crow >= climit) continue;
                    orow = ridx[crow];
                }
                const long ci = zC + orow * (long)N + ccol;
                if (C_BF16) ((unsigned short*)Cp)[ci] = f32_to_bf16(v);
                else        ((float*)Cp)[ci] = v;
            }
        }
    }
}

// ---------------------------------------------------------------------------
// transpose + f32->bf16:  src R x C (row-major, f32) -> dst C x R (bf16)
// ---------------------------------------------------------------------------
__global__ __launch_bounds__(256) void transpose_cvt(
    const float* __restrict__ src, unsigned short* __restrict__ dst,
    int R, int C, long sstride, long dstride)
{
    __shared__ float tile[32][33];
    const long sbase = (long)blockIdx.z * sstride;
    const long dbase = (long)blockIdx.z * dstride;
    const int c0 = blockIdx.x * 32;
    const int r0 = blockIdx.y * 32;
    const int tx = threadIdx.x & 31, ty = threadIdx.x >> 5;   // ty 0..7
#pragma unroll
    for (int i = 0; i < 32; i += 8)
        tile[ty + i][tx] = src[sbase + (long)(r0 + ty + i) * C + c0 + tx];
    __syncthreads();
#pragma unroll
    for (int i = 0; i < 32; i += 8)
        dst[dbase + (long)(c0 + ty + i) * R + r0 + tx] = f32_to_bf16(tile[tx][ty + i]);
}

// ---------------------------------------------------------------------------
// in-place row softmax over 2048 bf16 scores; one block per compacted row
// ---------------------------------------------------------------------------
__global__ __launch_bounds__(256) void softmax_rows(
    unsigned short* __restrict__ S, const int* __restrict__ padcnt)
{
    const int b = blockIdx.x >> 11, rc = blockIdx.x & 2047;
    if (rc >= padcnt[b]) return;
    const long base = (long)blockIdx.x * SEQ + threadIdx.x * 8;
    const int lane = threadIdx.x & 63, wave = threadIdx.x >> 6;
    __shared__ float rbuf[8];

    short8 v = *(const short8*)(S + base);
    float x[8];
#pragma unroll
    for (int j = 0; j < 8; ++j) x[j] = bf16_to_f32((unsigned short)v[j]);

    float m = x[0];
#pragma unroll
    for (int j = 1; j < 8; ++j) m = fmaxf(m, x[j]);
    for (int o = 32; o; o >>= 1) m = fmaxf(m, __shfl_xor(m, o));
    if (lane == 0) rbuf[wave] = m;
    __syncthreads();
    m = fmaxf(fmaxf(rbuf[0], rbuf[1]), fmaxf(rbuf[2], rbuf[3]));

    float e[8], s = 0.f;
#pragma unroll
    for (int j = 0; j < 8; ++j) { e[j] = __expf(x[j] - m); s += e[j]; }
    for (int o = 32; o; o >>= 1) s += __shfl_xor(s, o);
    if (lane == 0) rbuf[4 + wave] = s;
    __syncthreads();
    s = rbuf[4] + rbuf[5] + rbuf[6] + rbuf[7];
    const float inv = 1.0f / s;

    short8 o8;
#pragma unroll
    for (int j = 0; j < 8; ++j) o8[j] = (short)f32_to_bf16(e[j] * inv);
    *(short8*)(S + base) = o8;
}

// ---------------------------------------------------------------------------
// rows with mask<=0.5: out[b,i,:] = mavg[b,:]/masked_count  (exact fp32 path)
// ---------------------------------------------------------------------------
__global__ __launch_bounds__(256) void overwrite_masked(
    float* __restrict__ out, const float* __restrict__ mask,
    const float* __restrict__ mavg, const int* __restrict__ cnt)
{
    const int bid = blockIdx.x;            // b*SEQ + i
    const int b = bid >> 11;
    if (mask[bid] > 0.5f) return;
    const float inv = 1.0f / (float)(SEQ - cnt[b]);
    const long obase = (long)bid * DIM;
    const float* mv = mavg + b * DIM;
    for (int d = threadIdx.x; d < DIM; d += 256)
        out[obase + d] = mv[d] * inv;
}

extern "C" void kernel_launch(void* const* d_in, const int* in_sizes, int n_in,
                              void* d_out, int out_size, void* d_ws, size_t ws_size,
                              hipStream_t stream) {
    (void)in_sizes; (void)n_in; (void)out_size;
    const float* input_q = (const float*)d_in[0];
    const float* input_k = (const float*)d_in[1];
    const float* k_mask  = (const float*)d_in[2];
    const float* Wq      = (const float*)d_in[3];
    const float* bq      = (const float*)d_in[4];
    const float* Wk      = (const float*)d_in[5];
    const float* bk      = (const float*)d_in[6];
    float* out = (float*)d_out;

    // Workspace map. qc/kbf alias S (dead before scores GEMM writes S).
    char* ws = (char*)d_ws;
    unsigned short* qc   = (unsigned short*)(ws);                 // 32MB (aliases S lo)
    unsigned short* kbf  = (unsigned short*)(ws + 33554432);      // 32MB (aliases S hi)
    unsigned short* S    = (unsigned short*)(ws);                 // 64MB
    unsigned short* qp   = (unsigned short*)(ws + 67108864);      // 32MB
    unsigned short* kb   = (unsigned short*)(ws + 100663296);     // 32MB
    unsigned short* Vt   = (unsigned short*)(ws + 134217728);     // 32MB
    unsigned short* Wqt  = (unsigned short*)(ws + 167772160);     // 2MB
    unsigned short* Wkt  = (unsigned short*)(ws + 169869312);     // 2MB
    float*          mavg = (float*)(ws + 171966464);              // 32KB
    int*            idx  = (int*)(ws + 171999232);                // 64KB
    int*            cnts = (int*)(ws + 172064768);                // 32B
    int*            pcnt = (int*)(ws + 172064800);                // 32B
    if (ws_size < 172064832) return;

    hipMemsetAsync(mavg, 0, BATCH * DIM * sizeof(float), stream);

    build_idx<<<BATCH, 256, 0, stream>>>(k_mask, idx, cnts, pcnt);
    gather_cvt_q<<<dim3(SEQ, BATCH), 256, 0, stream>>>(input_q, idx, pcnt, qc);
    prep_k<<<dim3(BATCH, DIM / 256, SEQ / 256), 256, 0, stream>>>(input_k, k_mask, kbf, mavg);
    transpose_cvt<<<dim3(32, 32, 1), 256, 0, stream>>>(Wq, Wqt, DIM, DIM, 0, 0);
    transpose_cvt<<<dim3(32, 32, 1), 256, 0, stream>>>(Wk, Wkt, DIM, DIM, 0, 0);
    transpose_cvt<<<dim3(32, 64, BATCH), 256, 0, stream>>>(input_k, Vt, SEQ, DIM,
                                                           (long)SEQ * DIM, (long)DIM * SEQ);

    // q projection on compacted rows: per batch (padcnt x 1024) @ Wq^T + bq
    gemm_bt<true, true, true, false><<<dim3(16, 8, BATCH), 256, 0, stream>>>(
        qc, Wqt, qp, bq, DIM, DIM,
        (long)SEQ * DIM, 0, (long)SEQ * DIM, 1.0f, pcnt, nullptr, nullptr);
    // k projection, full 16384 rows flat
    gemm_bt<true, true, false, false><<<dim3(128, 8, 1), 256, 0, stream>>>(
        kbf, Wkt, kb, bk, DIM, DIM, 0, 0, 0, 1.0f, nullptr, nullptr, nullptr);

    // scores: per batch S[rc,:] = qp[rc] @ k^T / 32 -> bf16 (compacted rows)
    gemm_bt<true, false, true, false><<<dim3(16, 16, BATCH), 256, 0, stream>>>(
        qp, kb, S, nullptr, SEQ, DIM,
        (long)SEQ * DIM, (long)SEQ * DIM, (long)SEQ * SEQ, 0.03125f, pcnt, nullptr, nullptr);

    softmax_rows<<<BATCH * SEQ, 256, 0, stream>>>(S, pcnt);

    // out rows (scattered): per batch P @ V with row map idx
    gemm_bt<false, false, true, true><<<dim3(16, 8, BATCH), 256, 0, stream>>>(
        S, Vt, out, nullptr, DIM, SEQ,
        (long)SEQ * SEQ, (long)DIM * SEQ, (long)SEQ * DIM, 1.0f, pcnt, cnts, idx);

    overwrite_masked<<<BATCH * SEQ, 256, 0, stream>>>(out, k_mask, mavg, cnts);
}